// Round 11
// baseline (486.135 us; speedup 1.0000x reference)
//
#include <hip/hip_runtime.h>

// Problem constants (from reference)
#define B_      4
#define N_ATOMS 100000
#define D_      64
#define F_      8
#define G_      20000
#define A_      3
#define H_      16
#define AD_     (A_ * D_)                 // 192
#define BLOCK   256
#define GPB     64                         // cliques (g) per block
#define BSTRIDE ((size_t)N_ATOMS * D_)    // floats per batch slice
#define NTOT    ((size_t)B_ * N_ATOMS * D_)   // 25.6M table elements

// 16 FMAs: one x value against one W1 row (16 outputs) held in 4 float4s.
#define FMA16(x1, wr)                                            \
    {                                                            \
        const float4 w0 = (wr)[0], w1v = (wr)[1],                \
                     w2v = (wr)[2], w3v = (wr)[3];               \
        h[0]  = fmaf((x1), w0.x,  h[0]);                         \
        h[1]  = fmaf((x1), w0.y,  h[1]);                         \
        h[2]  = fmaf((x1), w0.z,  h[2]);                         \
        h[3]  = fmaf((x1), w0.w,  h[3]);                         \
        h[4]  = fmaf((x1), w1v.x, h[4]);                         \
        h[5]  = fmaf((x1), w1v.y, h[5]);                         \
        h[6]  = fmaf((x1), w1v.z, h[6]);                         \
        h[7]  = fmaf((x1), w1v.w, h[7]);                         \
        h[8]  = fmaf((x1), w2v.x, h[8]);                         \
        h[9]  = fmaf((x1), w2v.y, h[9]);                         \
        h[10] = fmaf((x1), w2v.z, h[10]);                        \
        h[11] = fmaf((x1), w2v.w, h[11]);                        \
        h[12] = fmaf((x1), w3v.x, h[12]);                        \
        h[13] = fmaf((x1), w3v.y, h[13]);                        \
        h[14] = fmaf((x1), w3v.z, h[14]);                        \
        h[15] = fmaf((x1), w3v.w, h[15]);                        \
    }

// Process one packed bf16 pair u = (k+1 | k): two FMA16 sweeps.
#define PAIR_BF16(u, kk)                                                     \
    {                                                                        \
        const float4* wr = (const float4*)&w1s[(size_t)(kk) * H_];           \
        const float flo = __uint_as_float((u) << 16);                        \
        const float fhi = __uint_as_float((u) & 0xffff0000u);                \
        FMA16(flo, wr);                                                      \
        FMA16(fhi, wr + 4);                                                  \
    }

// Consume one 64B line = 4 uint4 = 32 bf16 k-values (512 FMAs).
// kbase is wave-uniform -> LDS broadcast reads, conflict-free.
// R10 lesson: fully unrolled, this region has 128 ds_read_b128 of weights;
// the scheduler hoisted them -> VGPR=256 + 563 MB scratch spills. The f32
// kernel proved 64 live float4 reads fit at VGPR=168, so we fence every
// 2 PAIRs (16 float4 reads/region) with sched_barrier(0) — compile-time
// only, zero runtime cost — to bound the hoisting window.
#define COMPUTE_SEG_BF16(bufv, kbase)                                        \
    {                                                                        \
        _Pragma("unroll")                                                    \
        for (int q = 0; q < 4; ++q) {                                        \
            const uint4 uv = (bufv)[q];                                      \
            PAIR_BF16(uv.x, (kbase) + q * 8 + 0);                            \
            PAIR_BF16(uv.y, (kbase) + q * 8 + 2);                            \
            __builtin_amdgcn_sched_barrier(0);                               \
            PAIR_BF16(uv.z, (kbase) + q * 8 + 4);                            \
            PAIR_BF16(uv.w, (kbase) + q * 8 + 6);                            \
            __builtin_amdgcn_sched_barrier(0);                               \
        }                                                                    \
    }

// ---------------- pass 1: f32 table -> bf16 table in d_ws ----------------
__device__ __forceinline__ unsigned int bf16_rn(float x) {
    unsigned int u = __float_as_uint(x);
    return (u + 0x7fffu + ((u >> 16) & 1u)) >> 16;   // round-to-nearest-even
}

__global__ __launch_bounds__(256)
void convert_bf16_kernel(const float* __restrict__ atoms,
                         unsigned short* __restrict__ tab) {
    const size_t i = ((size_t)blockIdx.x * 256 + threadIdx.x) * 8;
    if (i >= NTOT) return;
    const float4 a = *(const float4*)(atoms + i);
    const float4 b = *(const float4*)(atoms + i + 4);
    uint4 o;
    o.x = bf16_rn(a.x) | (bf16_rn(a.y) << 16);
    o.y = bf16_rn(a.z) | (bf16_rn(a.w) << 16);
    o.z = bf16_rn(b.x) | (bf16_rn(b.y) << 16);
    o.w = bf16_rn(b.z) | (bf16_rn(b.w) << 16);
    *(uint4*)(tab + i) = o;
}

// ---------------- pass 2: gather (bf16) + per-formula MLP ----------------
// One thread = one (b, f, g). Block = one f, 64 consecutive g x 4 batches.
// Atom rows are 128 B (bf16) = 2 cache lines; read as 2 segments of
// 4 dwordx4, double-buffered; 512 FMAs cover each segment's 4 loads.
__global__ __launch_bounds__(BLOCK)
void cliques_mlp_bf16_kernel(const unsigned short* __restrict__ tab, // [B,N,D] bf16
                             const int*   __restrict__ gi,           // [F,G,A]
                             const float* __restrict__ W1,
                             const float* __restrict__ b1,
                             const float* __restrict__ W2,
                             const float* __restrict__ b2,
                             float* __restrict__ out) {
    __shared__ __align__(16) float w1s[AD_ * H_];   // 12 KiB
    __shared__ float b1s[H_];
    __shared__ float w2s[H_];
    __shared__ float b2s_s;
    __shared__ int   is64_s;

    const int f   = blockIdx.y;
    const int tid = threadIdx.x;

    {
        const float4* src = (const float4*)(W1 + (size_t)f * AD_ * H_);
        float4*       dst = (float4*)w1s;
        #pragma unroll
        for (int i = 0; i < (AD_ * H_) / 4; i += BLOCK)
            dst[i + tid] = src[i + tid];
    }
    if (tid < H_) {
        b1s[tid] = b1[f * H_ + tid];
        w2s[tid] = W2[f * H_ + tid];
    }
    if (tid == 0) {
        b2s_s = b2[f];
        // int64-vs-int32: indices < 1e5 => if buffer is int64 every odd
        // 32-bit word is 0. For int32 data P(32 random idx all 0) ~ 1e-160.
        unsigned ored = 0u;
        const unsigned* u = (const unsigned*)gi;
        #pragma unroll
        for (int i = 0; i < 32; ++i) ored |= u[2 * i + 1];
        is64_s = (ored == 0u) ? 1 : 0;
    }
    __syncthreads();

    const int lane = tid & 63;
    const int b    = tid >> 6;
    const int g    = blockIdx.x * GPB + lane;
    if (g >= G_) return;

    const long long eidx = ((long long)f * G_ + g) * A_;
    int i0, i1, i2;
    if (is64_s) {
        i0 = gi[2 * (eidx + 0)];
        i1 = gi[2 * (eidx + 1)];
        i2 = gi[2 * (eidx + 2)];
    } else {
        i0 = gi[eidx + 0];
        i1 = gi[eidx + 1];
        i2 = gi[eidx + 2];
    }

    const unsigned short* base = tab + (size_t)b * BSTRIDE;
    const uint4* rp0 = (const uint4*)(base + (size_t)i0 * D_);
    const uint4* rp1 = (const uint4*)(base + (size_t)i1 * D_);
    const uint4* rp2 = (const uint4*)(base + (size_t)i2 * D_);

    float h[H_];
    #pragma unroll
    for (int j = 0; j < H_; ++j) h[j] = b1s[j];

    // 6 segments: s = row*2 + half; each = one 64B line = 4 uint4.
    uint4 xa[4], xb[4];
    #pragma unroll
    for (int i = 0; i < 4; ++i) xa[i] = rp0[i];   // segment 0

    #pragma unroll 1
    for (int sp = 0; sp < 3; ++sp) {
        // prefetch odd segment 2*sp+1 into xb
        {
            const int so = 2 * sp + 1;
            const int ro = so >> 1, ho = so & 1;
            const uint4* po = (ro == 0) ? rp0 : (ro == 1) ? rp1 : rp2;
            po += ho * 4;
            #pragma unroll
            for (int i = 0; i < 4; ++i) xb[i] = po[i];
        }
        COMPUTE_SEG_BF16(xa, (2 * sp) * 32);

        // prefetch even segment 2*sp+2 into xa
        if (sp < 2) {
            const int se = 2 * sp + 2;
            const int re = se >> 1, he = se & 1;
            const uint4* pe = (re == 0) ? rp0 : (re == 1) ? rp1 : rp2;
            pe += he * 4;
            #pragma unroll
            for (int i = 0; i < 4; ++i) xa[i] = pe[i];
        }
        COMPUTE_SEG_BF16(xb, (2 * sp + 1) * 32);
    }

    float o = b2s_s;
    #pragma unroll
    for (int j = 0; j < H_; ++j) {
        const float s = 1.0f / (1.0f + __expf(-h[j]));
        o = fmaf(s, w2s[j], o);
    }
    o = 1.0f / (1.0f + __expf(-o));
    out[(size_t)b * (F_ * G_) + (size_t)f * G_ + g] = o;
}

// ---------------- fallback: f32 gather (ws too small) ----------------
#define COMPUTE_SEG4(bufv, kbase)                                            \
    {                                                                        \
        _Pragma("unroll")                                                    \
        for (int k4 = 0; k4 < 4; ++k4) {                                     \
            const float4 xv = (bufv)[k4];                                    \
            const float4* wr =                                               \
                (const float4*)&w1s[((kbase) + k4 * 4) * H_];                \
            FMA16(xv.x, wr + 0);                                             \
            FMA16(xv.y, wr + 4);                                             \
            FMA16(xv.z, wr + 8);                                             \
            FMA16(xv.w, wr + 12);                                            \
        }                                                                    \
    }

__global__ __launch_bounds__(BLOCK)
void cliques_mlp_kernel(const float* __restrict__ atoms,
                        const int*   __restrict__ gi,
                        const float* __restrict__ W1,
                        const float* __restrict__ b1,
                        const float* __restrict__ W2,
                        const float* __restrict__ b2,
                        float* __restrict__ out) {
    __shared__ __align__(16) float w1s[AD_ * H_];
    __shared__ float b1s[H_];
    __shared__ float w2s[H_];
    __shared__ float b2s_s;
    __shared__ int   is64_s;

    const int f   = blockIdx.y;
    const int tid = threadIdx.x;

    {
        const float4* src = (const float4*)(W1 + (size_t)f * AD_ * H_);
        float4*       dst = (float4*)w1s;
        #pragma unroll
        for (int i = 0; i < (AD_ * H_) / 4; i += BLOCK)
            dst[i + tid] = src[i + tid];
    }
    if (tid < H_) {
        b1s[tid] = b1[f * H_ + tid];
        w2s[tid] = W2[f * H_ + tid];
    }
    if (tid == 0) {
        b2s_s = b2[f];
        unsigned ored = 0u;
        const unsigned* u = (const unsigned*)gi;
        #pragma unroll
        for (int i = 0; i < 32; ++i) ored |= u[2 * i + 1];
        is64_s = (ored == 0u) ? 1 : 0;
    }
    __syncthreads();

    const int lane = tid & 63;
    const int b    = tid >> 6;
    const int g    = blockIdx.x * GPB + lane;
    if (g >= G_) return;

    const long long eidx = ((long long)f * G_ + g) * A_;
    int i0, i1, i2;
    if (is64_s) {
        i0 = gi[2 * (eidx + 0)];
        i1 = gi[2 * (eidx + 1)];
        i2 = gi[2 * (eidx + 2)];
    } else {
        i0 = gi[eidx + 0];
        i1 = gi[eidx + 1];
        i2 = gi[eidx + 2];
    }

    const float* base = atoms + (size_t)b * BSTRIDE;
    const float4* rp0 = (const float4*)(base + (size_t)i0 * D_);
    const float4* rp1 = (const float4*)(base + (size_t)i1 * D_);
    const float4* rp2 = (const float4*)(base + (size_t)i2 * D_);

    float h[H_];
    #pragma unroll
    for (int j = 0; j < H_; ++j) h[j] = b1s[j];

    float4 xa[4], xb[4];
    #pragma unroll
    for (int i = 0; i < 4; ++i) xa[i] = rp0[i];

    #pragma unroll 1
    for (int sp = 0; sp < 6; ++sp) {
        {
            const int so = 2 * sp + 1;
            const int ro = so >> 2, qo = so & 3;
            const float4* po = (ro == 0) ? rp0 : (ro == 1) ? rp1 : rp2;
            po += qo * 4;
            #pragma unroll
            for (int i = 0; i < 4; ++i) xb[i] = po[i];
        }
        COMPUTE_SEG4(xa, (2 * sp) * 16);

        if (sp < 5) {
            const int se = 2 * sp + 2;
            const int re = se >> 2, qe = se & 3;
            const float4* pe = (re == 0) ? rp0 : (re == 1) ? rp1 : rp2;
            pe += qe * 4;
            #pragma unroll
            for (int i = 0; i < 4; ++i) xa[i] = pe[i];
        }
        COMPUTE_SEG4(xb, (2 * sp + 1) * 16);
    }

    float o = b2s_s;
    #pragma unroll
    for (int j = 0; j < H_; ++j) {
        const float s = 1.0f / (1.0f + __expf(-h[j]));
        o = fmaf(s, w2s[j], o);
    }
    o = 1.0f / (1.0f + __expf(-o));
    out[(size_t)b * (F_ * G_) + (size_t)f * G_ + g] = o;
}

extern "C" void kernel_launch(void* const* d_in, const int* in_sizes, int n_in,
                              void* d_out, int out_size, void* d_ws, size_t ws_size,
                              hipStream_t stream) {
    const float* atoms = (const float*)d_in[0];
    const int*   gi    = (const int*)d_in[1];
    const float* W1    = (const float*)d_in[2];
    const float* b1    = (const float*)d_in[3];
    const float* W2    = (const float*)d_in[4];
    const float* b2    = (const float*)d_in[5];
    float*       out   = (float*)d_out;

    dim3 grid((G_ + GPB - 1) / GPB, F_);

    if (ws_size >= NTOT * sizeof(unsigned short)) {
        unsigned short* tab = (unsigned short*)d_ws;
        const int conv_blocks = (int)((NTOT / 8 + 255) / 256);
        convert_bf16_kernel<<<conv_blocks, 256, 0, stream>>>(atoms, tab);
        cliques_mlp_bf16_kernel<<<grid, dim3(BLOCK), 0, stream>>>(
            tab, gi, W1, b1, W2, b2, out);
    } else {
        cliques_mlp_kernel<<<grid, dim3(BLOCK), 0, stream>>>(
            atoms, gi, W1, b1, W2, b2, out);
    }
}

// Round 13
// 306.811 us; speedup vs baseline: 1.5845x; 1.5845x over previous
//
#include <hip/hip_runtime.h>

// Problem constants (from reference)
#define B_      4
#define N_ATOMS 100000
#define D_      64
#define F_      8
#define G_      20000
#define A_      3
#define H_      16
#define AD_     (A_ * D_)                 // 192
#define BLOCK   256
#define GPB     32                         // cliques (g) per block (2 lanes each)
#define BSTRIDE ((size_t)N_ATOMS * D_)    // floats per batch slice

// 16 FMAs: one x value against one W1 row (16 outputs) held in 4 float4s.
#define FMA16(x1, wr)                                            \
    {                                                            \
        const float4 w0 = (wr)[0], w1v = (wr)[1],                \
                     w2v = (wr)[2], w3v = (wr)[3];               \
        h[0]  = fmaf((x1), w0.x,  h[0]);                         \
        h[1]  = fmaf((x1), w0.y,  h[1]);                         \
        h[2]  = fmaf((x1), w0.z,  h[2]);                         \
        h[3]  = fmaf((x1), w0.w,  h[3]);                         \
        h[4]  = fmaf((x1), w1v.x, h[4]);                         \
        h[5]  = fmaf((x1), w1v.y, h[5]);                         \
        h[6]  = fmaf((x1), w1v.z, h[6]);                         \
        h[7]  = fmaf((x1), w1v.w, h[7]);                         \
        h[8]  = fmaf((x1), w2v.x, h[8]);                         \
        h[9]  = fmaf((x1), w2v.y, h[9]);                         \
        h[10] = fmaf((x1), w2v.z, h[10]);                        \
        h[11] = fmaf((x1), w2v.w, h[11]);                        \
        h[12] = fmaf((x1), w3v.x, h[12]);                        \
        h[13] = fmaf((x1), w3v.y, h[13]);                        \
        h[14] = fmaf((x1), w3v.z, h[14]);                        \
        h[15] = fmaf((x1), w3v.w, h[15]);                        \
    }

// Consume one 16-float quarter-row segment (4 float4, one 64B line).
// kbase differs between the two half-lanes (offset 96*16 floats = 1536 dw
// = 0 mod 32 banks -> 2-way same-bank LDS read, free per m136).
#define COMPUTE_SEG4(bufv, kbase)                                            \
    {                                                                        \
        _Pragma("unroll")                                                    \
        for (int k4 = 0; k4 < 4; ++k4) {                                     \
            const float4 xv = (bufv)[k4];                                    \
            const float4* wr =                                               \
                (const float4*)&w1s[((kbase) + k4 * 4) * H_];                \
            FMA16(xv.x, wr + 0);                                             \
            FMA16(xv.y, wr + 4);                                             \
            FMA16(xv.z, wr + 8);                                             \
            FMA16(xv.w, wr + 12);                                            \
        }                                                                    \
    }

// One clique = 2 lanes (k-halves of 96), halving the serial gather chain
// (R5 decision rule: latency-bound at 12 segments). Lane 2c+hh handles
// clique g = blk*32+c, k in [hh*96, hh*96+96) = 6 quarter-line segments.
// Wave w = batch w. Partial h reduced via __shfl_xor(.,1) at the end.
__global__ __launch_bounds__(BLOCK)
void cliques_mlp_kernel(const float* __restrict__ atoms,   // [B, N_ATOMS, D]
                        const int*   __restrict__ gi,      // [F,G,A] i32/i64 (detected)
                        const float* __restrict__ W1,      // [F, AD, H]
                        const float* __restrict__ b1,      // [F, H]
                        const float* __restrict__ W2,      // [F, H, 1]
                        const float* __restrict__ b2,      // [F, 1]
                        float* __restrict__ out)           // [B, F*G]
{
    __shared__ __align__(16) float w1s[AD_ * H_];   // 12 KiB
    __shared__ float b1s[H_];
    __shared__ float w2s[H_];
    __shared__ float b2s_s;
    __shared__ int   is64_s;

    const int f   = blockIdx.y;
    const int tid = threadIdx.x;

    // ---- stage per-formula weights into LDS (coalesced float4) ----
    {
        const float4* src = (const float4*)(W1 + (size_t)f * AD_ * H_);
        float4*       dst = (float4*)w1s;
        #pragma unroll
        for (int i = 0; i < (AD_ * H_) / 4; i += BLOCK)
            dst[i + tid] = src[i + tid];
    }
    if (tid < H_) {
        b1s[tid] = b1[f * H_ + tid];
        w2s[tid] = W2[f * H_ + tid];
    }
    if (tid == 0) {
        b2s_s = b2[f];
        // int64-vs-int32: indices < 1e5 => if buffer is int64 every odd
        // 32-bit word is 0. For int32 data P(32 random idx all 0) ~ 1e-160.
        unsigned ored = 0u;
        const unsigned* u = (const unsigned*)gi;
        #pragma unroll
        for (int i = 0; i < 32; ++i) ored |= u[2 * i + 1];
        is64_s = (ored == 0u) ? 1 : 0;
    }
    __syncthreads();

    const int lane = tid & 63;
    const int b    = tid >> 6;           // wave = batch
    const int c    = lane >> 1;          // clique within block (0..31)
    const int hh   = lane & 1;           // k-half (0: k<96, 1: k>=96)
    const int g    = blockIdx.x * GPB + c;   // G=20000=625*32: no tail

    // ---- 2 atom indices for this half (coalesced-ish across the wave) ----
    // half0 needs atoms 0,1 (k 0..95); half1 needs atoms 1,2 (k 96..191).
    const long long e3 = ((long long)f * G_ + g) * A_;
    int idx_lo, idx_hi;
    if (is64_s) {
        idx_lo = gi[2 * (e3 + hh)];
        idx_hi = gi[2 * (e3 + 1 + hh)];
    } else {
        idx_lo = gi[e3 + hh];
        idx_hi = gi[e3 + 1 + hh];
    }

    const float* base = atoms + (size_t)b * BSTRIDE;
    const float4* rp_lo = (const float4*)(base + (size_t)idx_lo * D_);
    const float4* rp_hi = (const float4*)(base + (size_t)idx_hi * D_);

    // segment s (0..5) -> pointer + quarter within that row:
    //  hh=0: s<4 -> rp_lo quarter s;     s>=4 -> rp_hi quarter s-4
    //  hh=1: s<2 -> rp_lo quarter s+2;   s>=2 -> rp_hi quarter s-2
    const int hh2    = 2 * hh;
    const int thresh = 4 - hh2;
#define SEGPTR(s) ( (((s) < thresh) ? rp_lo : rp_hi) +                       \
                    ((((s) < thresh) ? ((s) + hh2) : ((s) - thresh)) * 4) )

    const int khh = hh * 6 * 16;   // k-offset of this half's first segment

    float h[H_];
    #pragma unroll
    for (int j = 0; j < H_; ++j) h[j] = b1s[j];

    // ---- 6 quarter-line segments, double-buffered (proven R5 skeleton) ----
    float4 xa[4], xb[4];
    {
        const float4* p0 = SEGPTR(0);
        #pragma unroll
        for (int i = 0; i < 4; ++i) xa[i] = p0[i];
    }

    #pragma unroll 1
    for (int sp = 0; sp < 3; ++sp) {
        // prefetch odd segment 2*sp+1 into xb
        {
            const int so = 2 * sp + 1;
            const float4* po = SEGPTR(so);
            #pragma unroll
            for (int i = 0; i < 4; ++i) xb[i] = po[i];
        }
        // compute even segment 2*sp from xa (256 FMAs cover the loads)
        COMPUTE_SEG4(xa, khh + (2 * sp) * 16);

        // prefetch even segment 2*sp+2 into xa
        if (sp < 2) {
            const int se = 2 * sp + 2;
            const float4* pe = SEGPTR(se);
            #pragma unroll
            for (int i = 0; i < 4; ++i) xa[i] = pe[i];
        }
        // compute odd segment 2*sp+1 from xb
        COMPUTE_SEG4(xb, khh + (2 * sp + 1) * 16);
    }
#undef SEGPTR

    // ---- combine the two k-halves (lane pair) ----
    #pragma unroll
    for (int j = 0; j < H_; ++j)
        h[j] += __shfl_xor(h[j], 1);

    // ---- epilogue: sigmoid -> layer 2 -> sigmoid (both lanes, store even) ----
    float o = b2s_s;
    #pragma unroll
    for (int j = 0; j < H_; ++j) {
        const float s = 1.0f / (1.0f + __expf(-h[j]));
        o = fmaf(s, w2s[j], o);
    }
    o = 1.0f / (1.0f + __expf(-o));
    if (hh == 0)
        out[(size_t)b * (F_ * G_) + (size_t)f * G_ + g] = o;
}

extern "C" void kernel_launch(void* const* d_in, const int* in_sizes, int n_in,
                              void* d_out, int out_size, void* d_ws, size_t ws_size,
                              hipStream_t stream) {
    const float* atoms = (const float*)d_in[0];
    const int*   gi    = (const int*)d_in[1];
    const float* W1    = (const float*)d_in[2];
    const float* b1    = (const float*)d_in[3];
    const float* W2    = (const float*)d_in[4];
    const float* b2    = (const float*)d_in[5];
    float*       out   = (float*)d_out;

    dim3 grid(G_ / GPB, F_);   // 625 x 8, no tail (20000 = 625*32)
    cliques_mlp_kernel<<<grid, dim3(BLOCK), 0, stream>>>(atoms, gi, W1, b1, W2, b2, out);
}